// Round 4
// baseline (121.240 us; speedup 1.0000x reference)
//
#include <hip/hip_runtime.h>

// Problem constants: B=32, N=1024, F_IN=D=128
#define B    32
#define N    1024
#define FIN  128
#define CHN  16      // chunks per batch
#define ROWS 64      // rows per chunk
#define GRID (B * CHN)   // 512 blocks

// ws layout: [2*B] int counters, then floats
#define OFF_PASUM 64                        // [B][CHN][FIN]
#define OFF_U     (OFF_PASUM + B*CHN*FIN)   // [B][FIN]
#define OFF_C     (OFF_U + B*FIN)           // [B]
#define OFF_P     (OFF_C + B)               // [B][N]   p = exp(agg - Mc)
#define OFF_WPART (OFF_P + B*N)             // [B][CHN][FIN]
#define OFF_M     (OFF_WPART + B*CHN*FIN)   // [B][CHN]
#define OFF_L     (OFF_M + B*CHN)
#define OFF_S     (OFF_L + B*CHN)

__device__ __forceinline__ float aload(const float* p) {
    return __hip_atomic_load(p, __ATOMIC_RELAXED, __HIP_MEMORY_SCOPE_AGENT);
}
__device__ __forceinline__ void astore(float* p, float v) {
    __hip_atomic_store(p, v, __ATOMIC_RELAXED, __HIP_MEMORY_SCOPE_AGENT);
}

// ---- K1: per-chunk column sums; last block per batch computes ksum/u/c -----
__global__ __launch_bounds__(256) void k_pass1(
    const float* __restrict__ aq,
    const float* __restrict__ Wq, const float* __restrict__ bq,
    const float* __restrict__ Wk, const float* __restrict__ bk,
    float* __restrict__ ws)
{
    const int b = blockIdx.x >> 4, ch = blockIdx.x & 15;
    const int tid = threadIdx.x;
    int* cnt = (int*)ws;

    const float4* g4 = (const float4*)aq + ((size_t)b * N + ch * ROWS) * 32;
    float4 acc = make_float4(0.f, 0.f, 0.f, 0.f);
    #pragma unroll
    for (int i = 0; i < 8; ++i) {
        float4 v = g4[i * 256 + tid];
        acc.x += v.x; acc.y += v.y; acc.z += v.z; acc.w += v.w;
    }
    __shared__ float4 sh4[256];
    __shared__ int flag;
    sh4[tid] = acc;
    __syncthreads();
    if (tid < 32) {
        float4 r = sh4[tid];
        #pragma unroll
        for (int g = 1; g < 8; ++g) {
            float4 t = sh4[g * 32 + tid];
            r.x += t.x; r.y += t.y; r.z += t.z; r.w += t.w;
        }
        float* dst = ws + OFF_PASUM + (b * CHN + ch) * FIN + tid * 4;
        astore(dst + 0, r.x); astore(dst + 1, r.y);
        astore(dst + 2, r.z); astore(dst + 3, r.w);
    }
    __syncthreads();
    if (tid == 0) {
        __threadfence();
        int old = atomicAdd(&cnt[b], 1);
        flag = (old == CHN - 1);
    }
    __syncthreads();
    if (!flag) return;

    // ---- last block of batch b: asum -> ksum -> u, c (runs ONCE per batch)
    __threadfence();
    __shared__ float asum_s[FIN], ksum_s[FIN];
    __shared__ float red[256];
    const int f = tid & 127, h = tid >> 7;
    if (tid < FIN) {
        float a = 0.f;
        #pragma unroll
        for (int c = 0; c < CHN; ++c)
            a += aload(ws + OFF_PASUM + (b * CHN + c) * FIN + f);
        asum_s[f] = a;
    }
    __syncthreads();
    {
        float ks = 0.f;
        #pragma unroll 8
        for (int i = 0; i < 64; ++i) {
            int fi = h * 64 + i;
            ks += asum_s[fi] * Wk[fi * FIN + f];   // coalesced over f
        }
        red[tid] = ks;
    }
    __syncthreads();
    if (tid < FIN) ksum_s[f] = red[f] + red[f + 128] + 1024.f * bk[f];
    __syncthreads();
    {
        float uu = 0.f;
        #pragma unroll 8
        for (int i = 0; i < 64; ++i) {
            int d = h * 64 + i;
            uu += Wq[f * FIN + d] * ksum_s[d];
        }
        red[tid] = uu;
    }
    __syncthreads();
    if (tid < FIN) ws[OFF_U + b * FIN + f] = red[f] + red[f + 128];  // next kernel
    if (tid < 64) {
        float cc = bq[tid] * ksum_s[tid] + bq[tid + 64] * ksum_s[tid + 64];
        #pragma unroll
        for (int off = 32; off > 0; off >>= 1) cc += __shfl_xor(cc, off);
        if (tid == 0) ws[OFF_C + b] = cc;
    }
}

// ---- K2: agg + chunk stats + wpart; last block per batch does the combine --
__global__ __launch_bounds__(256) void k_main(
    const float* __restrict__ aq, const float* __restrict__ mask,
    const float* __restrict__ Wv, const float* __restrict__ bv,
    float* __restrict__ ws, float* __restrict__ out)
{
    const int b = blockIdx.x >> 4, ch = blockIdx.x & 15;
    const int tid = threadIdx.x, f = tid & 127, h = tid >> 7;
    int* cnt = (int*)ws;

    __shared__ float tile[ROWS * FIN];   // XOR-swizzled, 32 KB
    __shared__ float red[256];
    __shared__ float u_s[FIN], mp_s[ROWS];
    __shared__ float c_sh;
    __shared__ int flag;

    // stage tile (swizzle: float4 (r,j) -> r*32 + (j ^ (r&31)))
    {
        const float4* g4 = (const float4*)aq + ((size_t)b * N + ch * ROWS) * 32;
        float4* t4 = (float4*)tile;
        #pragma unroll
        for (int i = 0; i < 8; ++i) {
            int g = i * 256 + tid, row = g >> 5, c4 = g & 31;
            t4[row * 32 + (c4 ^ (row & 31))] = g4[g];
        }
    }
    if (tid < FIN) u_s[f] = ws[OFF_U + b * FIN + f];
    if (tid == 0) c_sh = ws[OFF_C + b];
    __syncthreads();

    // all 64 row-dots in parallel: thread (r = tid&63, q = tid>>6)
    {
        const int r = tid & 63, q = tid >> 6;
        const float4* t4 = (const float4*)tile;
        const float4* u4 = (const float4*)u_s;
        float acc = 0.f;
        #pragma unroll
        for (int jj = 0; jj < 8; ++jj) {
            int j = q * 8 + jj;
            float4 a = t4[r * 32 + (j ^ (r & 31))];
            float4 uu = u4[j];
            acc += a.x * uu.x + a.y * uu.y + a.z * uu.z + a.w * uu.w;
        }
        red[tid] = acc;
    }
    __syncthreads();
    if (tid < ROWS) {
        const float dkc = 0.08838834764831845f;   // 128^-0.5
        float dot = red[tid] + red[tid + 64] + red[tid + 128] + red[tid + 192];
        float m = mask[b * N + ch * ROWS + tid];
        float aggv = m * (dkc * (dot + c_sh)) + (1.f - m) * (-1e9f);
        float Mc = aggv;
        #pragma unroll
        for (int off = 32; off > 0; off >>= 1) Mc = fmaxf(Mc, __shfl_xor(Mc, off));
        float p = __expf(aggv - Mc);              // masked rows -> exact 0
        float mp = m * p;
        astore(ws + OFF_P + b * N + ch * ROWS + tid, p);
        mp_s[tid] = mp;
        float Lc = p, Sc = mp;
        #pragma unroll
        for (int off = 32; off > 0; off >>= 1) {
            Lc += __shfl_xor(Lc, off);
            Sc += __shfl_xor(Sc, off);
        }
        if (tid == 0) {
            astore(ws + OFF_M + b * CHN + ch, Mc);
            astore(ws + OFF_L + b * CHN + ch, Lc);
            astore(ws + OFF_S + b * CHN + ch, Sc);
        }
    }
    __syncthreads();
    // wpart[f] = sum_r mp[r] * aq[r][f]
    {
        float w = 0.f;
        #pragma unroll 8
        for (int i = 0; i < 32; ++i) {
            int r = h * 32 + i;
            w += mp_s[r] * tile[r * FIN + ((((f >> 2) ^ (r & 31)) << 2) | (f & 3))];
        }
        red[tid] = w;
    }
    __syncthreads();
    if (tid < FIN) astore(ws + OFF_WPART + (b * CHN + ch) * FIN + f, red[f] + red[f + 128]);
    __syncthreads();
    if (tid == 0) {
        __threadfence();
        int old = atomicAdd(&cnt[B + b], 1);
        flag = (old == CHN - 1);
    }
    __syncthreads();
    if (!flag) return;

    // ---- last block of batch b: cross-chunk combine + attn + context
    __threadfence();
    float M = -3.0e38f;
    #pragma unroll
    for (int c = 0; c < CHN; ++c) M = fmaxf(M, aload(ws + OFF_M + b * CHN + c));
    float Em[CHN], L = 0.f, S = 0.f;
    #pragma unroll
    for (int c = 0; c < CHN; ++c) {
        float e = __expf(aload(ws + OFF_M + b * CHN + c) - M);
        Em[c] = e;
        L += e * aload(ws + OFF_L + b * CHN + c);
        S += e * aload(ws + OFF_S + b * CHN + c);
    }
    const float invL = 1.f / L;
    #pragma unroll
    for (int j = 0; j < 4; ++j) {
        int n = j * 256 + tid;                 // chunk = j*4 + (tid>>6)
        out[b * N + n] = aload(ws + OFF_P + b * N + n) * Em[j * 4 + (tid >> 6)] * invL;
    }
    if (tid < FIN) {
        float w = 0.f;
        #pragma unroll
        for (int c = 0; c < CHN; ++c)
            w += Em[c] * aload(ws + OFF_WPART + (b * CHN + c) * FIN + f);
        u_s[f] = w;                            // reuse as wsh
    }
    __syncthreads();
    {
        float ctx = 0.f;
        #pragma unroll 8
        for (int i = 0; i < 64; ++i) {
            int fi = h * 64 + i;
            ctx += u_s[fi] * Wv[fi * FIN + f]; // coalesced over f
        }
        red[tid] = ctx;
    }
    __syncthreads();
    if (tid < FIN)
        out[B * N + b * FIN + f] = (red[f] + red[f + 128]) * invL + S * invL * bv[f];
}

extern "C" void kernel_launch(void* const* d_in, const int* in_sizes, int n_in,
                              void* d_out, int out_size, void* d_ws, size_t ws_size,
                              hipStream_t stream) {
    const float* aq   = (const float*)d_in[0];
    const float* mask = (const float*)d_in[1];
    const float* Wq   = (const float*)d_in[2];
    const float* bq   = (const float*)d_in[3];
    const float* Wk   = (const float*)d_in[4];
    const float* bk   = (const float*)d_in[5];
    const float* Wv   = (const float*)d_in[6];
    const float* bv   = (const float*)d_in[7];
    float* ws  = (float*)d_ws;
    float* out = (float*)d_out;

    // zero the 2*B block-arrival counters (256 B) — graph-capturable async op
    hipMemsetAsync(ws, 0, 2 * B * sizeof(int), stream);
    k_pass1<<<GRID, 256, 0, stream>>>(aq, Wq, bq, Wk, bk, ws);
    k_main <<<GRID, 256, 0, stream>>>(aq, mask, Wv, bv, ws, out);
}

// Round 5
// 99.232 us; speedup vs baseline: 1.2218x; 1.2218x over previous
//
#include <hip/hip_runtime.h>

// Problem constants: B=32, N=1024, F_IN=D=128
#define B    32
#define N    1024
#define FIN  128
#define CHN  16      // chunks per batch
#define ROWS 64      // rows per chunk
#define GRID (B * CHN)   // 512 blocks

// ws float offsets
#define OFF_PASUM 0                         // [B][CHN][FIN] column partial sums
#define OFF_P     (B * CHN * FIN)           // [B][N]  p = exp(agg - Mc), 0 for masked
#define OFF_WPART (OFF_P + B * N)           // [B][CHN][FIN] sum of m*p*aq
#define OFF_M     (OFF_WPART + B * CHN * FIN)  // [B][CHN]
#define OFF_L     (OFF_M + B * CHN)
#define OFF_S     (OFF_L + B * CHN)

// ---------------- K1: per-chunk column sums of atom_query -------------------
__global__ __launch_bounds__(256) void k_asum(const float* __restrict__ aq,
                                              float* __restrict__ ws) {
    const int b = blockIdx.x >> 4, ch = blockIdx.x & 15;
    const float4* g4 = (const float4*)aq + ((size_t)b * N + ch * ROWS) * 32;
    float4 acc = make_float4(0.f, 0.f, 0.f, 0.f);
    #pragma unroll
    for (int i = 0; i < 8; ++i) {
        float4 v = g4[i * 256 + threadIdx.x];
        acc.x += v.x; acc.y += v.y; acc.z += v.z; acc.w += v.w;
    }
    __shared__ float4 sh[256];
    sh[threadIdx.x] = acc;
    __syncthreads();
    if (threadIdx.x < 32) {
        float4 r = sh[threadIdx.x];
        #pragma unroll
        for (int g = 1; g < 8; ++g) {
            float4 t = sh[g * 32 + threadIdx.x];
            r.x += t.x; r.y += t.y; r.z += t.z; r.w += t.w;
        }
        float4* outp = (float4*)(ws + OFF_PASUM) + (b * CHN + ch) * 32;
        outp[threadIdx.x] = r;
    }
}

// ---------------- K2: prep (redundant) + agg + chunk stats + wpart ----------
__global__ __launch_bounds__(256) void k_main(
    const float* __restrict__ aq, const float* __restrict__ mask,
    const float* __restrict__ Wq, const float* __restrict__ bq,
    const float* __restrict__ Wk, const float* __restrict__ bk,
    float* __restrict__ ws)
{
    const int b = blockIdx.x >> 4, ch = blockIdx.x & 15;
    const int tid = threadIdx.x, f = tid & 127, h = tid >> 7;

    __shared__ float tile[ROWS * FIN];        // XOR-swizzled, 32 KB
    __shared__ float red[256];
    __shared__ float asum_s[FIN], ksum_s[FIN], u_s[FIN], mp_s[ROWS];
    __shared__ float c_sh;

    // Issue the tile staging loads FIRST; they drain while prep computes.
    float4 stage[8];
    const float4* g4 = (const float4*)aq + ((size_t)b * N + ch * ROWS) * 32;
    #pragma unroll
    for (int i = 0; i < 8; ++i) stage[i] = g4[i * 256 + tid];

    // ---- prep: asum -> ksum -> u, c (redundant per block; Wk/Wq L2-hot)
    {
        float a = 0.f;
        #pragma unroll
        for (int c = 0; c < 8; ++c)
            a += ws[OFF_PASUM + (b * CHN + h * 8 + c) * FIN + f];
        red[tid] = a;
    }
    __syncthreads();
    if (tid < FIN) asum_s[f] = red[f] + red[f + 128];
    __syncthreads();
    {
        float ks = 0.f;
        #pragma unroll 8
        for (int i = 0; i < 64; ++i) {
            int fi = h * 64 + i;
            ks += asum_s[fi] * Wk[fi * FIN + f];      // coalesced over f
        }
        red[tid] = ks;
    }
    __syncthreads();
    if (tid < FIN) ksum_s[f] = red[f] + red[f + 128] + 1024.f * bk[f];
    __syncthreads();
    {
        float uu = 0.f;
        #pragma unroll 8
        for (int i = 0; i < 64; ++i) {
            int d = h * 64 + i;
            uu += Wq[f * FIN + d] * ksum_s[d];        // L1/L2-amortized
        }
        red[tid] = uu;
    }
    __syncthreads();
    if (tid < FIN) u_s[f] = red[f] + red[f + 128];
    if (tid < 64) {
        float cc = bq[tid] * ksum_s[tid] + bq[tid + 64] * ksum_s[tid + 64];
        #pragma unroll
        for (int off = 32; off > 0; off >>= 1) cc += __shfl_xor(cc, off);
        if (tid == 0) c_sh = cc;
    }
    // ---- commit staged tile (swizzle: float4 (r,j) -> r*32 + (j ^ (r&31)))
    {
        float4* t4 = (float4*)tile;
        #pragma unroll
        for (int i = 0; i < 8; ++i) {
            int g = i * 256 + tid;
            int row = g >> 5, c4 = g & 31;
            t4[row * 32 + (c4 ^ (row & 31))] = stage[i];
        }
    }
    __syncthreads();

    // ---- all 64 row-dots in parallel: thread (r = tid&63, q = tid>>6)
    {
        const int r = tid & 63, q = tid >> 6;
        const float4* t4 = (const float4*)tile;
        const float4* u4 = (const float4*)u_s;
        float acc = 0.f;
        #pragma unroll
        for (int jj = 0; jj < 8; ++jj) {
            int j = q * 8 + jj;
            float4 a = t4[r * 32 + (j ^ (r & 31))];
            float4 uu = u4[j];                        // wave-uniform
            acc += a.x * uu.x + a.y * uu.y + a.z * uu.z + a.w * uu.w;
        }
        red[tid] = acc;
    }
    __syncthreads();
    if (tid < ROWS) {
        const float dkc = 0.08838834764831845f;       // 128^-0.5
        float dot = red[tid] + red[tid + 64] + red[tid + 128] + red[tid + 192];
        float m = mask[b * N + ch * ROWS + tid];      // coalesced
        float raw = dkc * (dot + c_sh);
        float aggv = m * raw + (1.f - m) * (-1e9f);
        float Mc = aggv;
        #pragma unroll
        for (int off = 32; off > 0; off >>= 1) Mc = fmaxf(Mc, __shfl_xor(Mc, off));
        float p = __expf(aggv - Mc);                  // masked rows -> exact 0
        float mp = m * p;
        ws[OFF_P + b * N + ch * ROWS + tid] = p;
        mp_s[tid] = mp;
        float Lc = p, Sc = mp;
        #pragma unroll
        for (int off = 32; off > 0; off >>= 1) {
            Lc += __shfl_xor(Lc, off);
            Sc += __shfl_xor(Sc, off);
        }
        if (tid == 0) {
            ws[OFF_M + b * CHN + ch] = Mc;
            ws[OFF_L + b * CHN + ch] = Lc;
            ws[OFF_S + b * CHN + ch] = Sc;
        }
    }
    __syncthreads();
    // ---- weighted column sums: wpart[f] = sum_r mp[r] * aq[r][f]
    {
        float w = 0.f;
        #pragma unroll 8
        for (int i = 0; i < 32; ++i) {
            int r = h * 32 + i;
            w += mp_s[r] * tile[r * FIN + ((((f >> 2) ^ (r & 31)) << 2) | (f & 3))];
        }
        red[tid] = w;
    }
    __syncthreads();
    if (tid < FIN)
        ws[OFF_WPART + (b * CHN + ch) * FIN + f] = red[f] + red[f + 128];
}

// ---------------- K3: cross-chunk combine + attn + context ------------------
// grid 128 (= B*4), block 256. Each block handles 256 attn rows; sub==0 also
// computes the context row for its batch.
__global__ __launch_bounds__(256) void k_final(const float* __restrict__ Wv,
                                               const float* __restrict__ bv,
                                               const float* __restrict__ ws,
                                               float* __restrict__ out) {
    const int b = blockIdx.x >> 2, sub = blockIdx.x & 3;
    const int tid = threadIdx.x, f = tid & 127, h = tid >> 7;
    float M = -3.0e38f;
    #pragma unroll
    for (int c = 0; c < CHN; ++c) M = fmaxf(M, ws[OFF_M + b * CHN + c]);
    float Em[CHN], L = 0.f, S = 0.f;
    #pragma unroll
    for (int c = 0; c < CHN; ++c) {
        float e = __expf(ws[OFF_M + b * CHN + c] - M);
        Em[c] = e;
        L += e * ws[OFF_L + b * CHN + c];
        S += e * ws[OFF_S + b * CHN + c];
    }
    const float invL = 1.f / L;
    // attn = p * Em[chunk] * invL  (one row per thread, coalesced)
    {
        int n = sub * 256 + tid;               // chunk = sub*4 + (tid>>6)
        out[b * N + n] = ws[OFF_P + b * N + n] * Em[sub * 4 + (tid >> 6)] * invL;
    }
    if (sub != 0) return;
    // context
    __shared__ float wsh[FIN];
    __shared__ float red[256];
    {
        float w = 0.f;
        #pragma unroll
        for (int c = 0; c < 8; ++c)
            w += Em[h * 8 + c] * ws[OFF_WPART + (b * CHN + h * 8 + c) * FIN + f];
        red[tid] = w;
    }
    __syncthreads();
    if (tid < FIN) wsh[f] = red[f] + red[f + 128];
    __syncthreads();
    {
        float ctx = 0.f;
        #pragma unroll 8
        for (int i = 0; i < 64; ++i) {
            int fi = h * 64 + i;
            ctx += wsh[fi] * Wv[fi * FIN + f];        // coalesced over f
        }
        red[tid] = ctx;
    }
    __syncthreads();
    if (tid < FIN)
        out[B * N + b * FIN + f] = (red[f] + red[f + 128]) * invL + S * invL * bv[f];
}

extern "C" void kernel_launch(void* const* d_in, const int* in_sizes, int n_in,
                              void* d_out, int out_size, void* d_ws, size_t ws_size,
                              hipStream_t stream) {
    const float* aq   = (const float*)d_in[0];
    const float* mask = (const float*)d_in[1];
    const float* Wq   = (const float*)d_in[2];
    const float* bq   = (const float*)d_in[3];
    const float* Wk   = (const float*)d_in[4];
    const float* bk   = (const float*)d_in[5];
    const float* Wv   = (const float*)d_in[6];
    const float* bv   = (const float*)d_in[7];
    float* ws  = (float*)d_ws;
    float* out = (float*)d_out;

    k_asum <<<GRID,  256, 0, stream>>>(aq, ws);
    k_main <<<GRID,  256, 0, stream>>>(aq, mask, Wq, bq, Wk, bk, ws);
    k_final<<<B * 4, 256, 0, stream>>>(Wv, bv, ws, out);
}